// Round 5
// baseline (2661.481 us; speedup 1.0000x reference)
//
#include <hip/hip_runtime.h>
#include <hip/hip_fp16.h>

#define DT 5e-5f
#define SPRING_Y 30000.0f
#define DASHPOT 100.0f
// exp(-DT * DRAG_DAMPING) = exp(-5e-5)
#define DRAG 0.9999500012499792f
#define NSUB 100

// xv layout: xv[2*i] = position, xv[2*i+1] = velocity (w unused); 32B/vertex,
// both halves in one 64B line. adj entry: 4B: (nbr:17)<<15 | (fp16(1/rest)&0x7fff).
// Row: vertex v's entries at adj[v*64 .. v*64+deg[v]).
// R15 = R1's proven substep (8 lanes/vertex, scalar adj loads, 2 pair-steps
// per superiteration, pair-cooperative 64B line gathers) + DEGREE-SORTED
// vertex grouping: perm[] orders vertices by degree, so the 8 vertices in a
// wave have near-equal deg. A wave runs to the MAX degree of its vertices
// (all eval slots issue 2 gather-addrs + 1 adj-addr even when masked), so
// equalizing deg within waves cuts issued memory requests ~1.7x -> ~1.1x of
// the real-spring floor. FP math per vertex is unchanged (only grouping).

// ---------- build ----------

__global__ void init_k(const float* __restrict__ x0, float4* __restrict__ xv,
                       int* __restrict__ deg, int* __restrict__ cnt, int nv) {
    int i = blockIdx.x * blockDim.x + threadIdx.x;
    if (i < nv) {
        xv[2 * i]     = make_float4(x0[3 * i], x0[3 * i + 1], x0[3 * i + 2], 0.0f);
        xv[2 * i + 1] = make_float4(0.0f, 0.0f, 0.0f, 0.0f);
        deg[i] = 0;
    }
    if (i < 130) cnt[i] = 0;           // histogram + bucket-ptr area
}

__global__ void fill_sliced_k(const int2* __restrict__ springs,
                              const float* __restrict__ rest,
                              int* __restrict__ deg, unsigned* __restrict__ adj,
                              int ns, int nv, int S) {
    int b = blockIdx.x;
    int slice = b & 7;
    int s = (b >> 3) * blockDim.x + threadIdx.x;
    if (s >= ns) return;

    int lo = (int)(((long long)slice * nv) >> 3);
    int hi = (int)(((long long)(slice + 1) * nv) >> 3);

    int2 p = springs[s];
    unsigned h = __half_as_ushort(__float2half(1.0f / rest[s])) & 0x7fffu;
    if (p.x >= lo && p.x < hi) {
        int a = atomicAdd(&deg[p.x], 1);
        adj[p.x * S + a] = ((unsigned)p.y << 15) | h;
    }
    if (p.y >= lo && p.y < hi) {
        int c = atomicAdd(&deg[p.y], 1);
        adj[p.y * S + c] = ((unsigned)p.x << 15) | h;
    }
}

// histogram of degrees (buckets 0..64; deg>64 would have overflowed adj anyway)
__global__ void hist_k(const int* __restrict__ deg, int* __restrict__ cnt, int nv) {
    int v = blockIdx.x * blockDim.x + threadIdx.x;
    if (v < nv) atomicAdd(&cnt[min(deg[v], 64)], 1);
}

// exclusive scan of 65 buckets into cnt[65..129] (single thread; trivial size)
__global__ void scan_k(int* __restrict__ cnt) {
    if (blockIdx.x == 0 && threadIdx.x == 0) {
        int run = 0;
        for (int i = 0; i <= 64; ++i) {
            cnt[65 + i] = run;
            run += cnt[i];
        }
    }
}

// scatter vertices into degree-sorted order
__global__ void scatter_k(const int* __restrict__ deg, int* __restrict__ cnt,
                          int* __restrict__ perm, int nv) {
    int v = blockIdx.x * blockDim.x + threadIdx.x;
    if (v >= nv) return;
    int b = min(deg[v], 64);
    int pos = atomicAdd(&cnt[65 + b], 1);
    perm[pos] = v;
}

// ---------- fused per-substep kernel (R1 body + perm) ----------

// one eval: lane computes its OWN entry's spring contribution.
// t1 = xvin[2*nA + par]   (even lane: pos(A); odd lane: vel(A))
// t2 = xvin[2*nB + 1-par] (even lane: vel(B); odd lane: pos(B))
__device__ __forceinline__ void spring_accum(
        int par, unsigned e, float msk, float4 t1, float4 t2,
        const float4& xa, const float4& va,
        float& fx, float& fy, float& fz) {
    float invr = __uint_as_float(((e & 0x7fffu) << 13) + (112u << 23));
    float xbx = par ? t2.x : t1.x;     // own neighbor's position
    float xby = par ? t2.y : t1.y;
    float xbz = par ? t2.z : t1.z;
    float ux  = par ? t1.x : t2.x;     // half this lane must SEND (partner's vel)
    float uy  = par ? t1.y : t2.y;
    float uz  = par ? t1.z : t2.z;
    float vbx = __shfl_xor(ux, 1);     // own neighbor's velocity
    float vby = __shfl_xor(uy, 1);
    float vbz = __shfl_xor(uz, 1);

    float dx = xbx - xa.x, dy = xby - xa.y, dz = xbz - xa.z;
    float len = sqrtf(dx * dx + dy * dy + dz * dz);
    float il = 1.0f / len;             // clamped dups are valid entries: len > 0
    float ddx = dx * il, ddy = dy * il, ddz = dz * il;
    float vrel = (vbx - va.x) * ddx + (vby - va.y) * ddy + (vbz - va.z) * ddz;
    float coef = (SPRING_Y * (len * invr - 1.0f) + DASHPOT * vrel) * msk;
    fx += coef * ddx;
    fy += coef * ddy;
    fz += coef * ddz;
}

__global__ void __launch_bounds__(256) substep_k(
        const float4* __restrict__ xvin, float4* __restrict__ xvout,
        const unsigned* __restrict__ adj, const int* __restrict__ deg,
        const int* __restrict__ perm,
        const float* __restrict__ mass, int nv, int S,
        float* __restrict__ out) {
    int gid = blockIdx.x * blockDim.x + threadIdx.x;
    int g   = gid >> 3;
    int sub = gid & 7;
    if (g >= nv) return;
    int vid = perm[g];                 // degree-sorted grouping (same line for
                                       // all 8 lanes of the group)

    float4 xa = xvin[2 * vid];
    float4 va = xvin[2 * vid + 1];
    float m = mass[vid];               // hoisted: overlaps with loop latency
    int d = deg[vid];
    int s0 = vid * S;
    int last = s0 + d - 1;             // valid when d > 0
    int par  = sub & 1;                // lane parity within its pair
    int base = sub & ~1;               // pair's entry offset within the row
    int niter = (d > base) ? ((d - base + 7) >> 3) : 0;  // pair-steps
    int pf = s0 + base;

    float fx = 0.0f, fy = 0.0f, fz = 0.0f;

    // 2 pair-steps per superiteration: 4 adj loads + 4 line-gathers all
    // issue before any shuffle/compute.
    for (int u = 0; u < niter; u += 2) {
        int pb0 = pf + 8 * u;
        int pb1 = pb0 + 8;
        // both lanes of the pair load BOTH entries (same cache line; clamped:
        // never touches uninitialized adj slots)
        unsigned eA0 = adj[min(pb0,     last)];
        unsigned eB0 = adj[min(pb0 + 1, last)];
        unsigned eA1 = adj[min(pb1,     last)];
        unsigned eB1 = adj[min(pb1 + 1, last)];
        int nA0 = (int)(eA0 >> 15), nB0 = (int)(eB0 >> 15);
        int nA1 = (int)(eA1 >> 15), nB1 = (int)(eB1 >> 15);

        // cooperative line fetches, all independent (masked steps re-fetch the
        // clamped line -> L1 hit)
        float4 t10 = xvin[2 * nA0 + par];
        float4 t20 = xvin[2 * nB0 + (1 - par)];
        float4 t11 = xvin[2 * nA1 + par];
        float4 t21 = xvin[2 * nB1 + (1 - par)];

        {   // step 0
            float msk = (pb0 + par <= last) ? 1.0f : 0.0f;
            spring_accum(par, par ? eB0 : eA0, msk, t10, t20, xa, va, fx, fy, fz);
        }
        {   // step 1 (fully masked when niter is odd and u+1 == niter)
            float msk = (pb1 + par <= last) ? 1.0f : 0.0f;
            spring_accum(par, par ? eB1 : eA1, msk, t11, t21, xa, va, fx, fy, fz);
        }
    }

    // reduce across the 8 lanes of this vertex (xor stays within the group)
    fx += __shfl_xor(fx, 1);
    fx += __shfl_xor(fx, 2);
    fx += __shfl_xor(fx, 4);
    fy += __shfl_xor(fy, 1);
    fy += __shfl_xor(fy, 2);
    fy += __shfl_xor(fy, 4);
    fz += __shfl_xor(fz, 1);
    fz += __shfl_xor(fz, 2);
    fz += __shfl_xor(fz, 4);

    if (sub == 0) {
        fz += m * (-9.8f);
        float invm = 1.0f / m;

        va.x = (va.x + DT * fx * invm) * DRAG;
        va.y = (va.y + DT * fy * invm) * DRAG;
        va.z = (va.z + DT * fz * invm) * DRAG;

        xa.x += DT * va.x;
        xa.y += DT * va.y;
        xa.z += DT * va.z;
        xa.z = fmaxf(xa.z, 0.0f);
        if (xa.z == 0.0f) va.z = 0.0f;

        xvout[2 * vid]     = xa;
        xvout[2 * vid + 1] = va;

        if (out) {                     // final substep: emit packed (NV,3) output
            out[3 * vid + 0] = xa.x;
            out[3 * vid + 1] = xa.y;
            out[3 * vid + 2] = xa.z;
        }
    }
}

extern "C" void kernel_launch(void* const* d_in, const int* in_sizes, int n_in,
                              void* d_out, int out_size, void* d_ws, size_t ws_size,
                              hipStream_t stream) {
    const float* x0      = (const float*)d_in[0];   // (NV,3) fp32
    const int2*  springs = (const int2*)d_in[1];    // (NS,2) int32
    const float* rest    = (const float*)d_in[2];   // (NS,)  fp32
    const float* mass    = (const float*)d_in[3];   // (NV,)  fp32

    const int ns = in_sizes[2];        // 1,000,000
    const int nv = in_sizes[3];        // 100,000
    const int nb = (nv + 255) / 256;

    // workspace layout
    char* ws = (char*)d_ws;
    size_t o = 0;
    float4* xva   = (float4*)(ws + o); o += (size_t)nv * 32;   // x,v interleaved
    float4* xvb   = (float4*)(ws + o); o += (size_t)nv * 32;
    int* deg      = (int*)(ws + o);    o += (((size_t)nv * 4 + 15) & ~15ull);
    int* perm     = (int*)(ws + o);    o += (((size_t)nv * 4 + 15) & ~15ull);
    int* cnt      = (int*)(ws + o);    o += 130 * 4 + 8;       // hist + bucket ptrs
    o = (o + 15) & ~15ull;
    unsigned* adj = (unsigned*)(ws + o);                       // nv*64*4B = 25.6MB

    const int STRIDE = 64;

    dim3 blk(256);
    dim3 vgrid(nb);
    dim3 fgrid(8 * ((ns + 255) / 256));           // 8 slices x spring chunks
    dim3 subgrid(((size_t)nv * 8 + 255) / 256);   // 8 lanes per vertex

    // build (replayed every call; amortized over 100 substeps)
    init_k<<<vgrid, blk, 0, stream>>>(x0, xva, deg, cnt, nv);
    fill_sliced_k<<<fgrid, blk, 0, stream>>>(springs, rest, deg, adj, ns, nv, STRIDE);
    hist_k<<<vgrid, blk, 0, stream>>>(deg, cnt, nv);
    scan_k<<<dim3(1), dim3(64), 0, stream>>>(cnt);
    scatter_k<<<vgrid, blk, 0, stream>>>(deg, cnt, perm, nv);

    float4* xi = xva;
    float4* xo = xvb;
    for (int t = 0; t < NSUB; ++t) {
        float* out = (t == NSUB - 1) ? (float*)d_out : nullptr;
        substep_k<<<subgrid, blk, 0, stream>>>(xi, xo, adj, deg, perm, mass, nv,
                                               STRIDE, out);
        float4* tmp = xi; xi = xo; xo = tmp;
    }
}

// Round 6
// 1869.396 us; speedup vs baseline: 1.4237x; 1.4237x over previous
//
#include <hip/hip_runtime.h>
#include <hip/hip_fp16.h>

#define DT 5e-5f
#define SPRING_Y 30000.0f
#define DASHPOT 100.0f
// exp(-DT * DRAG_DAMPING) = exp(-5e-5)
#define DRAG 0.9999500012499792f
#define NSUB 100

// xv layout: xv[2*i] = position, xv[2*i+1] = velocity (w unused); 32B/vertex,
// both halves in one 64B line. adj entry: 4B: (nbr:17)<<15 | (fp16(1/rest)&0x7fff).
// R16 = R1's proven substep (8 lanes/vertex, scalar adj loads, 2 pair-steps per
// superiteration, pair-cooperative 64B line gathers) with the adjacency packed
// as exact CSR (8 MB total vs 25.6 MB stride-64). Rationale: steady-state
// substep traffic is L2/L3 (R4: first-substep FETCH ~= compulsory, hbm ~= 0);
// per-XCD hot set (xin 3.2 MB + touched adj) exceeded the 4 MB L2 -> random
// gathers spilled to Infinity Cache. CSR drops the per-XCD adj slice to ~1 MB
// (and densifies row lines), pulling the hot set to ~L2 size. Block->XCD
// round-robin is launch-stable, so each XCD's CSR slice stays L2-hot across
// all 100 substeps. Build = count -> block-scan (no hot-address atomics,
// R5's scatter_k burned 276 us on 65-address atomics) -> sliced place.

// ---------- build ----------

__global__ void init_k(const float* __restrict__ x0, float4* __restrict__ xv,
                       int* __restrict__ deg, int nv) {
    int i = blockIdx.x * blockDim.x + threadIdx.x;
    if (i < nv) {
        xv[2 * i]     = make_float4(x0[3 * i], x0[3 * i + 1], x0[3 * i + 2], 0.0f);
        xv[2 * i + 1] = make_float4(0.0f, 0.0f, 0.0f, 0.0f);
        deg[i] = 0;
    }
}

// degree count: atomics over 100K addresses (low contention)
__global__ void count_k(const int2* __restrict__ springs, int* __restrict__ deg,
                        int ns) {
    int s = blockIdx.x * blockDim.x + threadIdx.x;
    if (s >= ns) return;
    int2 p = springs[s];
    atomicAdd(&deg[p.x], 1);
    atomicAdd(&deg[p.y], 1);
}

// exclusive scan of deg -> rowstart, 3 phases (no single-address atomics)
__global__ void scan1_k(const int* __restrict__ deg, int* __restrict__ rowstart,
                        int* __restrict__ bsum, int nv) {
    __shared__ int sh[256];
    int t = threadIdx.x;
    int i = blockIdx.x * 256 + t;
    int v = (i < nv) ? deg[i] : 0;
    sh[t] = v;
    __syncthreads();
    for (int off = 1; off < 256; off <<= 1) {      // Hillis-Steele inclusive
        int add = (t >= off) ? sh[t - off] : 0;
        __syncthreads();
        sh[t] += add;
        __syncthreads();
    }
    if (i < nv) rowstart[i] = sh[t] - v;           // local exclusive
    if (t == 255) bsum[blockIdx.x] = sh[255];      // block total
}

__global__ void scan2_k(int* __restrict__ bsum, int nb) {
    if (blockIdx.x == 0 && threadIdx.x == 0) {
        int run = 0;
        for (int i = 0; i < nb; ++i) { int x = bsum[i]; bsum[i] = run; run += x; }
    }
}

__global__ void scan3_k(int* __restrict__ rowstart, const int* __restrict__ bsum,
                        int* __restrict__ cursor, int nv) {
    int i = blockIdx.x * blockDim.x + threadIdx.x;
    if (i < nv) {
        int r = rowstart[i] + bsum[blockIdx.x];
        rowstart[i] = r;
        cursor[i]   = r;                           // place-pass allocation cursor
    }
}

// sliced CSR place: 8 vertex slices; block b handles spring chunk b>>3 and
// writes only endpoints in slice b&7 (round-robin pins slice<->XCD -> writes
// coalesce in that L2)
__global__ void place_sliced_k(const int2* __restrict__ springs,
                               const float* __restrict__ rest,
                               int* __restrict__ cursor, unsigned* __restrict__ csr,
                               int ns, int nv) {
    int b = blockIdx.x;
    int slice = b & 7;
    int s = (b >> 3) * blockDim.x + threadIdx.x;
    if (s >= ns) return;

    int lo = (int)(((long long)slice * nv) >> 3);
    int hi = (int)(((long long)(slice + 1) * nv) >> 3);

    int2 p = springs[s];
    unsigned h = __half_as_ushort(__float2half(1.0f / rest[s])) & 0x7fffu;
    if (p.x >= lo && p.x < hi)
        csr[atomicAdd(&cursor[p.x], 1)] = ((unsigned)p.y << 15) | h;
    if (p.y >= lo && p.y < hi)
        csr[atomicAdd(&cursor[p.y], 1)] = ((unsigned)p.x << 15) | h;
}

// ---------- fused per-substep kernel (R1 body, CSR base) ----------

// one eval: lane computes its OWN entry's spring contribution.
// t1 = xvin[2*nA + par]   (even lane: pos(A); odd lane: vel(A))
// t2 = xvin[2*nB + 1-par] (even lane: vel(B); odd lane: pos(B))
__device__ __forceinline__ void spring_accum(
        int par, unsigned e, float msk, float4 t1, float4 t2,
        const float4& xa, const float4& va,
        float& fx, float& fy, float& fz) {
    float invr = __uint_as_float(((e & 0x7fffu) << 13) + (112u << 23));
    float xbx = par ? t2.x : t1.x;     // own neighbor's position
    float xby = par ? t2.y : t1.y;
    float xbz = par ? t2.z : t1.z;
    float ux  = par ? t1.x : t2.x;     // half this lane must SEND (partner's vel)
    float uy  = par ? t1.y : t2.y;
    float uz  = par ? t1.z : t2.z;
    float vbx = __shfl_xor(ux, 1);     // own neighbor's velocity
    float vby = __shfl_xor(uy, 1);
    float vbz = __shfl_xor(uz, 1);

    float dx = xbx - xa.x, dy = xby - xa.y, dz = xbz - xa.z;
    float len = sqrtf(dx * dx + dy * dy + dz * dz);
    float il = 1.0f / len;             // clamped dups are valid entries: len > 0
    float ddx = dx * il, ddy = dy * il, ddz = dz * il;
    float vrel = (vbx - va.x) * ddx + (vby - va.y) * ddy + (vbz - va.z) * ddz;
    float coef = (SPRING_Y * (len * invr - 1.0f) + DASHPOT * vrel) * msk;
    fx += coef * ddx;
    fy += coef * ddy;
    fz += coef * ddz;
}

__global__ void __launch_bounds__(256) substep_k(
        const float4* __restrict__ xvin, float4* __restrict__ xvout,
        const unsigned* __restrict__ adj, const int* __restrict__ deg,
        const int* __restrict__ rowstart,
        const float* __restrict__ mass, int nv,
        float* __restrict__ out) {
    int gid = blockIdx.x * blockDim.x + threadIdx.x;
    int vid = gid >> 3;
    int sub = gid & 7;
    if (vid >= nv) return;

    float4 xa = xvin[2 * vid];
    float4 va = xvin[2 * vid + 1];
    float m = mass[vid];               // hoisted: overlaps with loop latency
    int d  = deg[vid];
    int s0 = rowstart[vid];            // CSR row base
    int last = s0 + d - 1;             // valid when d > 0
    int par  = sub & 1;                // lane parity within its pair
    int base = sub & ~1;               // pair's entry offset within the row
    int niter = (d > base) ? ((d - base + 7) >> 3) : 0;  // pair-steps
    int pf = s0 + base;

    float fx = 0.0f, fy = 0.0f, fz = 0.0f;

    // 2 pair-steps per superiteration: 4 adj loads + 4 line-gathers all
    // issue before any shuffle/compute.
    for (int u = 0; u < niter; u += 2) {
        int pb0 = pf + 8 * u;
        int pb1 = pb0 + 8;
        // both lanes of the pair load BOTH entries (same cache line; clamp
        // keeps reads inside this row -> never uninitialized)
        unsigned eA0 = adj[min(pb0,     last)];
        unsigned eB0 = adj[min(pb0 + 1, last)];
        unsigned eA1 = adj[min(pb1,     last)];
        unsigned eB1 = adj[min(pb1 + 1, last)];
        int nA0 = (int)(eA0 >> 15), nB0 = (int)(eB0 >> 15);
        int nA1 = (int)(eA1 >> 15), nB1 = (int)(eB1 >> 15);

        // cooperative line fetches, all independent (masked steps re-fetch the
        // clamped line -> L1 hit)
        float4 t10 = xvin[2 * nA0 + par];
        float4 t20 = xvin[2 * nB0 + (1 - par)];
        float4 t11 = xvin[2 * nA1 + par];
        float4 t21 = xvin[2 * nB1 + (1 - par)];

        {   // step 0
            float msk = (pb0 + par <= last) ? 1.0f : 0.0f;
            spring_accum(par, par ? eB0 : eA0, msk, t10, t20, xa, va, fx, fy, fz);
        }
        {   // step 1 (fully masked when niter is odd and u+1 == niter)
            float msk = (pb1 + par <= last) ? 1.0f : 0.0f;
            spring_accum(par, par ? eB1 : eA1, msk, t11, t21, xa, va, fx, fy, fz);
        }
    }

    // reduce across the 8 lanes of this vertex (xor stays within the group)
    fx += __shfl_xor(fx, 1);
    fx += __shfl_xor(fx, 2);
    fx += __shfl_xor(fx, 4);
    fy += __shfl_xor(fy, 1);
    fy += __shfl_xor(fy, 2);
    fy += __shfl_xor(fy, 4);
    fz += __shfl_xor(fz, 1);
    fz += __shfl_xor(fz, 2);
    fz += __shfl_xor(fz, 4);

    if (sub == 0) {
        fz += m * (-9.8f);
        float invm = 1.0f / m;

        va.x = (va.x + DT * fx * invm) * DRAG;
        va.y = (va.y + DT * fy * invm) * DRAG;
        va.z = (va.z + DT * fz * invm) * DRAG;

        xa.x += DT * va.x;
        xa.y += DT * va.y;
        xa.z += DT * va.z;
        xa.z = fmaxf(xa.z, 0.0f);
        if (xa.z == 0.0f) va.z = 0.0f;

        xvout[2 * vid]     = xa;
        xvout[2 * vid + 1] = va;

        if (out) {                     // final substep: emit packed (NV,3) output
            out[3 * vid + 0] = xa.x;
            out[3 * vid + 1] = xa.y;
            out[3 * vid + 2] = xa.z;
        }
    }
}

extern "C" void kernel_launch(void* const* d_in, const int* in_sizes, int n_in,
                              void* d_out, int out_size, void* d_ws, size_t ws_size,
                              hipStream_t stream) {
    const float* x0      = (const float*)d_in[0];   // (NV,3) fp32
    const int2*  springs = (const int2*)d_in[1];    // (NS,2) int32
    const float* rest    = (const float*)d_in[2];   // (NS,)  fp32
    const float* mass    = (const float*)d_in[3];   // (NV,)  fp32

    const int ns = in_sizes[2];        // 1,000,000
    const int nv = in_sizes[3];        // 100,000
    const int nb = (nv + 255) / 256;   // 391

    // workspace layout (~16 MB total)
    char* ws = (char*)d_ws;
    size_t o = 0;
    float4* xva   = (float4*)(ws + o); o += (size_t)nv * 32;   // x,v interleaved
    float4* xvb   = (float4*)(ws + o); o += (size_t)nv * 32;
    int* deg      = (int*)(ws + o);    o += (((size_t)nv * 4 + 15) & ~15ull);
    int* rowstart = (int*)(ws + o);    o += (((size_t)nv * 4 + 15) & ~15ull);
    int* cursor   = (int*)(ws + o);    o += (((size_t)nv * 4 + 15) & ~15ull);
    int* bsum     = (int*)(ws + o);    o += 512 * 4;           // block sums (nb<=512)
    unsigned* csr = (unsigned*)(ws + o);                       // 2*ns*4B = 8 MB

    dim3 blk(256);
    dim3 vgrid(nb);
    dim3 sgrid((ns + 255) / 256);
    dim3 pgrid(8 * ((ns + 255) / 256));            // 8 slices x spring chunks
    dim3 subgrid(((size_t)nv * 8 + 255) / 256);    // 8 lanes per vertex

    // build (replayed every call; amortized over 100 substeps)
    init_k<<<vgrid, blk, 0, stream>>>(x0, xva, deg, nv);
    count_k<<<sgrid, blk, 0, stream>>>(springs, deg, ns);
    scan1_k<<<vgrid, blk, 0, stream>>>(deg, rowstart, bsum, nv);
    scan2_k<<<dim3(1), dim3(64), 0, stream>>>(bsum, nb);
    scan3_k<<<vgrid, blk, 0, stream>>>(rowstart, bsum, cursor, nv);
    place_sliced_k<<<pgrid, blk, 0, stream>>>(springs, rest, cursor, csr, ns, nv);

    float4* xi = xva;
    float4* xo = xvb;
    for (int t = 0; t < NSUB; ++t) {
        float* out = (t == NSUB - 1) ? (float*)d_out : nullptr;
        substep_k<<<subgrid, blk, 0, stream>>>(xi, xo, csr, deg, rowstart,
                                               mass, nv, out);
        float4* tmp = xi; xi = xo; xo = tmp;
    }
}